// Round 1
// baseline (5368.911 us; speedup 1.0000x reference)
//
#include <hip/hip_runtime.h>
#include <cstdint>

#define NTHREADS 512
#define L_SEQ 2048
#define D_DIM 1024
#define BQ 64
#define BK 32
#define KST 1032   // K_lds row stride (bf16 elems): 2064B, 16B-aligned rows, 2-way banks
#define VST 34     // Vt_lds row stride (bf16): 68B, conflict-free transpose writes
#define SST 36     // S_lds row stride (floats): 2-way banks for MFMA-layout atomics
#define PST 40     // P_lds row stride (bf16): 80B, 16B-aligned quad offsets

#define K_OFF 0
#define K_BYTES (BK * KST * 2)            // 66048
#define V_OFF (K_OFF + K_BYTES)           // 66048
#define V_BYTES (D_DIM * VST * 2)         // 69632
#define S_OFF (V_OFF + V_BYTES)           // 135680
#define S_BYTES (BQ * SST * 4)            // 9216
#define P_OFF (S_OFF + S_BYTES)           // 144896
#define P_BYTES (BQ * PST * 2)            // 5120
#define M_OFF (P_OFF + P_BYTES)           // 150016
#define LDS_TOTAL (M_OFF + BQ * 4 * 3 + 16)  // 150800 < 160 KiB

typedef unsigned int u32;
typedef __bf16 bf16x8 __attribute__((ext_vector_type(8)));
typedef float f32x4 __attribute__((ext_vector_type(4)));

__device__ __forceinline__ f32x4 mfma16(int4 a, int4 b, f32x4 c) {
  return __builtin_amdgcn_mfma_f32_16x16x32_bf16(
      __builtin_bit_cast(bf16x8, a), __builtin_bit_cast(bf16x8, b), c, 0, 0, 0);
}

// pack two fp32 -> bf16x2 (round-to-nearest, ties away): 4 VALU
__device__ __forceinline__ u32 pk2(float a, float b) {
  u32 ua = __float_as_uint(a) + 0x8000u;
  u32 ub = __float_as_uint(b) + 0x8000u;
  return (ua >> 16) | (ub & 0xffff0000u);
}

__global__ __launch_bounds__(NTHREADS, 2)
void fa_fwd(const float* __restrict__ Qg, const float* __restrict__ Kg,
            const float* __restrict__ Vg, float* __restrict__ Og) {
  extern __shared__ char smem[];
  unsigned short* Ksh = (unsigned short*)(smem + K_OFF);   // [BK][KST] bf16, row-major
  unsigned short* Vtsh = (unsigned short*)(smem + V_OFF);  // [D_DIM][VST] bf16, transposed V
  float* Ssh = (float*)(smem + S_OFF);                     // [BQ][SST] f32 scores
  unsigned short* Psh = (unsigned short*)(smem + P_OFF);   // [BQ][PST] bf16 probs
  float* msh = (float*)(smem + M_OFF);                     // [BQ] running max (log2 dom)
  float* lsh = msh + BQ;                                   // [BQ] running denom
  float* ash = lsh + BQ;                                   // [BQ] alpha this iter
  int* fsh = (int*)(ash + BQ);                             // [4] per-16-row rescale flags

  const int tid = threadIdx.x;
  const int lane = tid & 63;
  const int wave = tid >> 6;   // d-slice owner: cols [wave*128, wave*128+128)
  const int r = lane & 15;
  const int quad = lane >> 4;

  const int qtile = (int)gridDim.x - 1 - (int)blockIdx.x;  // heavy tiles dispatch first
  const int q0 = qtile * BQ;
  const int b = blockIdx.y;
  const size_t base = (size_t)b * L_SEQ * D_DIM;
  const float* Qb = Qg + base;
  const float* Kb = Kg + base;
  const float* Vb = Vg + base;
  float* Ob = Og + base;

  // ---- Q fragments, bf16, persistent: A[m=lane&15][k=quad*8+j] over this wave's d-slice ----
  int4 qf[4][4];
#pragma unroll
  for (int m = 0; m < 4; ++m)
#pragma unroll
    for (int ks = 0; ks < 4; ++ks) {
      const float* src = Qb + (size_t)(q0 + m * 16 + r) * D_DIM + wave * 128 + ks * 32 + quad * 8;
      float4 x = *(const float4*)src;
      float4 y = *(const float4*)(src + 4);
      qf[m][ks] = make_int4((int)pk2(x.x, x.y), (int)pk2(x.z, x.w),
                            (int)pk2(y.x, y.y), (int)pk2(y.z, y.w));
    }

  // ---- O accumulators: O[64 rows][this wave's 128 cols] ----
  f32x4 o[4][8];
  const f32x4 fzero = {0.f, 0.f, 0.f, 0.f};
#pragma unroll
  for (int m = 0; m < 4; ++m)
#pragma unroll
    for (int n = 0; n < 8; ++n) o[m][n] = fzero;

  if (tid < BQ) { msh[tid] = -3.0e38f; lsh[tid] = 0.f; }

  const int nkt = q0 / BK + 2;                // causal tile skip
  const float SC = 0.04508422002778011f;      // log2(e) / sqrt(1024)

  for (int kt = 0; kt < nkt; ++kt) {
    __syncthreads();  // (1) prev-iter LDS consumers done

    // ---- stage K tile [BK][D] fp32->bf16 (row-major) ----
    {
      const float* Ks = Kb + (size_t)kt * BK * D_DIM;
#pragma unroll 8
      for (int i = 0; i < 16; ++i) {
        int u = i * NTHREADS + tid;
        int key = u >> 8;
        int c = u & 255;
        float4 v = *(const float4*)(Ks + key * D_DIM + c * 4);
        *(uint2*)&Ksh[key * KST + c * 4] = make_uint2(pk2(v.x, v.y), pk2(v.z, v.w));
      }
      // ---- stage V tile transposed: Vt[d][key] bf16 ----
      const float* Vs = Vb + (size_t)kt * BK * D_DIM;
#pragma unroll 8
      for (int i = 0; i < 32; ++i) {
        int u = i * NTHREADS + tid;
        int kp = u >> 10;      // key pair 0..15
        int d = u & 1023;
        float a = Vs[kp * 2 * D_DIM + d];
        float c2 = Vs[(kp * 2 + 1) * D_DIM + d];
        *(u32*)&Vtsh[d * VST + kp * 2] = pk2(a, c2);
      }
      // zero score buffer + flags
      int q = tid >> 3, k4 = (tid & 7) * 4;
      *(float4*)&Ssh[q * SST + k4] = make_float4(0.f, 0.f, 0.f, 0.f);
      if (tid < 4) fsh[tid] = 0;
    }
    __syncthreads();  // (2) tiles staged

    // ---- QK^T partial over this wave's 128-d slice, reduce via LDS atomics ----
    {
      f32x4 sp[4][2];
#pragma unroll
      for (int m = 0; m < 4; ++m) { sp[m][0] = fzero; sp[m][1] = fzero; }
#pragma unroll
      for (int ks = 0; ks < 4; ++ks) {
        int dcol = wave * 128 + ks * 32 + quad * 8;
        int4 kb0 = *(int4*)&Ksh[r * KST + dcol];          // keys 0..15
        int4 kb1 = *(int4*)&Ksh[(16 + r) * KST + dcol];   // keys 16..31
#pragma unroll
        for (int m = 0; m < 4; ++m) {
          sp[m][0] = mfma16(qf[m][ks], kb0, sp[m][0]);
          sp[m][1] = mfma16(qf[m][ks], kb1, sp[m][1]);
        }
      }
#pragma unroll
      for (int m = 0; m < 4; ++m)
#pragma unroll
        for (int n = 0; n < 2; ++n)
#pragma unroll
          for (int i = 0; i < 4; ++i)
            atomicAdd(&Ssh[(m * 16 + quad * 4 + i) * SST + n * 16 + r], sp[m][n][i]);
    }
    __syncthreads();  // (3) S complete

    // ---- online softmax: 8 threads per row ----
    {
      int q = tid >> 3, kk = (tid & 7) * 4;
      float4 sv = *(float4*)&Ssh[q * SST + kk];
      int qglob = q0 + q, kglob = kt * BK + kk;
      float e0 = (kglob <= qglob) ? sv.x * SC : -1e30f;
      float e1 = (kglob + 1 <= qglob) ? sv.y * SC : -1e30f;
      float e2 = (kglob + 2 <= qglob) ? sv.z * SC : -1e30f;
      float e3 = (kglob + 3 <= qglob) ? sv.w * SC : -1e30f;
      float mx = fmaxf(fmaxf(e0, e1), fmaxf(e2, e3));
      mx = fmaxf(mx, __shfl_xor(mx, 1));
      mx = fmaxf(mx, __shfl_xor(mx, 2));
      mx = fmaxf(mx, __shfl_xor(mx, 4));
      float mprev = msh[q], lprev = lsh[q];
      float mnew = fmaxf(mprev, mx);
      float alpha = exp2f(mprev - mnew);
      float p0 = exp2f(e0 - mnew), p1 = exp2f(e1 - mnew);
      float p2 = exp2f(e2 - mnew), p3 = exp2f(e3 - mnew);
      float sum = (p0 + p1) + (p2 + p3);
      sum += __shfl_xor(sum, 1);
      sum += __shfl_xor(sum, 2);
      sum += __shfl_xor(sum, 4);
      *(uint2*)&Psh[q * PST + kk] = make_uint2(pk2(p0, p1), pk2(p2, p3));
      if ((tid & 7) == 0) {
        msh[q] = mnew;
        lsh[q] = lprev * alpha + sum;
        ash[q] = alpha;
        if (alpha != 1.0f) fsh[q >> 4] = 1;  // same-value racy store: fine
      }
    }
    __syncthreads();  // (4) P/alpha ready

    // ---- conditional O rescale + PV ----
    {
#pragma unroll
      for (int m = 0; m < 4; ++m) {
        if (fsh[m]) {  // wave-uniform; rarely taken after max saturates
          float a0 = ash[m * 16 + quad * 4 + 0];
          float a1 = ash[m * 16 + quad * 4 + 1];
          float a2 = ash[m * 16 + quad * 4 + 2];
          float a3 = ash[m * 16 + quad * 4 + 3];
#pragma unroll
          for (int n = 0; n < 8; ++n) {
            o[m][n][0] *= a0; o[m][n][1] *= a1; o[m][n][2] *= a2; o[m][n][3] *= a3;
          }
        }
      }
      int4 pf[4];
#pragma unroll
      for (int m = 0; m < 4; ++m)
        pf[m] = *(int4*)&Psh[(m * 16 + r) * PST + quad * 8];
#pragma unroll
      for (int n = 0; n < 8; ++n) {
        const unsigned short* vp = &Vtsh[(wave * 128 + n * 16 + r) * VST + quad * 8];
        int4 vb = make_int4(*(const u32*)vp, *(const u32*)(vp + 2),
                            *(const u32*)(vp + 4), *(const u32*)(vp + 6));
#pragma unroll
        for (int m = 0; m < 4; ++m) o[m][n] = mfma16(pf[m], vb, o[m][n]);
      }
    }
  }

  // ---- epilogue: O / l ----
#pragma unroll
  for (int m = 0; m < 4; ++m) {
    float inv0 = 1.0f / lsh[m * 16 + quad * 4 + 0];
    float inv1 = 1.0f / lsh[m * 16 + quad * 4 + 1];
    float inv2 = 1.0f / lsh[m * 16 + quad * 4 + 2];
    float inv3 = 1.0f / lsh[m * 16 + quad * 4 + 3];
#pragma unroll
    for (int n = 0; n < 8; ++n) {
      size_t row = (size_t)q0 + m * 16 + quad * 4;
      size_t col = (size_t)wave * 128 + n * 16 + r;
      Ob[(row + 0) * D_DIM + col] = o[m][n][0] * inv0;
      Ob[(row + 1) * D_DIM + col] = o[m][n][1] * inv1;
      Ob[(row + 2) * D_DIM + col] = o[m][n][2] * inv2;
      Ob[(row + 3) * D_DIM + col] = o[m][n][3] * inv3;
    }
  }
}

extern "C" void kernel_launch(void* const* d_in, const int* in_sizes, int n_in,
                              void* d_out, int out_size, void* d_ws, size_t ws_size,
                              hipStream_t stream) {
  const float* Q = (const float*)d_in[0];
  const float* K = (const float*)d_in[1];
  const float* V = (const float*)d_in[2];
  float* O = (float*)d_out;
  int B = in_sizes[0] / (L_SEQ * D_DIM);

  // dynamic LDS > 64 KiB needs the attribute (idempotent; not a stream op -> capture-safe)
  hipFuncSetAttribute((const void*)fa_fwd, hipFuncAttributeMaxDynamicSharedMemorySize,
                      LDS_TOTAL);

  dim3 grid(L_SEQ / BQ, B);
  fa_fwd<<<grid, NTHREADS, LDS_TOTAL, stream>>>(Q, K, V, O);
}

// Round 2
// 2510.388 us; speedup vs baseline: 2.1387x; 2.1387x over previous
//
#include <hip/hip_runtime.h>
#include <cstdint>

#define NTHREADS 512
#define L_SEQ 2048
#define D_DIM 1024
#define BQ 64
#define BK 32
#define KST 1032   // K_lds row stride (bf16 elems): 2064B rows; b128 frag reads hit all 32 banks
#define VST 34     // Vt_lds row stride (bf16): 68B, 2-way (free) reads+writes
#define SST 36     // S_lds row stride (ints): conflict-free ds_add pattern
#define PST 40     // P_lds row stride (bf16): 80B, 16B-aligned quad offsets

#define K_OFF 0
#define K_BYTES (BK * KST * 2)            // 66048
#define V_OFF (K_OFF + K_BYTES)           // 66048
#define V_BYTES (D_DIM * VST * 2)         // 69632
#define S_OFF (V_OFF + V_BYTES)           // 135680
#define S_BYTES (BQ * SST * 4)            // 9216
#define P_OFF (S_OFF + S_BYTES)           // 144896
#define P_BYTES (BQ * PST * 2)            // 5120
#define M_OFF (P_OFF + P_BYTES)           // 150016
#define LDS_TOTAL (M_OFF + BQ * 4 * 3 + 16)  // 150800 < 160 KiB

typedef unsigned int u32;
typedef __bf16 bf16x8 __attribute__((ext_vector_type(8)));
typedef float f32x4 __attribute__((ext_vector_type(4)));

__device__ __forceinline__ f32x4 mfma16(int4 a, int4 b, f32x4 c) {
  return __builtin_amdgcn_mfma_f32_16x16x32_bf16(
      __builtin_bit_cast(bf16x8, a), __builtin_bit_cast(bf16x8, b), c, 0, 0, 0);
}

// pack two fp32 -> bf16x2
__device__ __forceinline__ u32 pk2(float a, float b) {
  u32 ua = __float_as_uint(a) + 0x8000u;
  u32 ub = __float_as_uint(b) + 0x8000u;
  return (ua >> 16) | (ub & 0xffff0000u);
}

// S fixed-point scale: scores |.| < ~400, 400*4096 << 2^31
#define SFIX 4096.0f

__global__ __attribute__((amdgpu_waves_per_eu(2, 2))) __launch_bounds__(NTHREADS)
void fa_fwd(const float* __restrict__ Qg, const float* __restrict__ Kg,
            const float* __restrict__ Vg, float* __restrict__ Og) {
  extern __shared__ char smem[];
  unsigned short* Ksh = (unsigned short*)(smem + K_OFF);   // [BK][KST] bf16, row-major
  unsigned short* Vtsh = (unsigned short*)(smem + V_OFF);  // [D_DIM][VST] bf16, transposed V
  int* Ssh = (int*)(smem + S_OFF);                         // [BQ][SST] fixed-point scores
  unsigned short* Psh = (unsigned short*)(smem + P_OFF);   // [BQ][PST] bf16 probs
  float* msh = (float*)(smem + M_OFF);                     // [BQ] running max (log2 dom)
  float* lsh = msh + BQ;                                   // [BQ] running denom
  float* ash = lsh + BQ;                                   // [BQ] alpha this iter
  int* fsh = (int*)(ash + BQ);                             // [4] per-16-row rescale flags

  const int tid = threadIdx.x;
  const int lane = tid & 63;
  const int wave = tid >> 6;   // d-slice owner: cols [wave*128, wave*128+128)
  const int r = lane & 15;
  const int quad = lane >> 4;

  const int qtile = (int)gridDim.x - 1 - (int)blockIdx.x;  // heavy tiles dispatch first
  const int q0 = qtile * BQ;
  const int b = blockIdx.y;
  const size_t base = (size_t)b * L_SEQ * D_DIM;
  const float* Qb = Qg + base;
  const float* Kb = Kg + base;
  const float* Vb = Vg + base;
  float* Ob = Og + base;

  // ---- Q fragments, bf16, persistent: A[m=lane&15][k=quad*8+j] over this wave's d-slice ----
  int4 qf[4][4];
#pragma unroll
  for (int m = 0; m < 4; ++m)
#pragma unroll
    for (int ks = 0; ks < 4; ++ks) {
      const float* src = Qb + (size_t)(q0 + m * 16 + r) * D_DIM + wave * 128 + ks * 32 + quad * 8;
      float4 x = *(const float4*)src;
      float4 y = *(const float4*)(src + 4);
      qf[m][ks] = make_int4((int)pk2(x.x, x.y), (int)pk2(x.z, x.w),
                            (int)pk2(y.x, y.y), (int)pk2(y.z, y.w));
    }

  // ---- O accumulators: O[64 rows][this wave's 128 cols] ----
  f32x4 o[4][8];
  const f32x4 fzero = {0.f, 0.f, 0.f, 0.f};
#pragma unroll
  for (int m = 0; m < 4; ++m)
#pragma unroll
    for (int n = 0; n < 8; ++n) o[m][n] = fzero;

  if (tid < BQ) { msh[tid] = -3.0e38f; lsh[tid] = 0.f; }

  const int nkt = q0 / BK + 2;                // causal tile skip
  const float SC = 0.04508422002778011f;      // log2(e) / sqrt(1024)
  const float SCI = SC / SFIX;                // applied to fixed-point S

  for (int kt = 0; kt < nkt; ++kt) {
    __syncthreads();  // (1) prev-iter LDS consumers done

    // ---- stage K tile [BK][D] fp32->bf16 (row-major) ----
    {
      const float* Ks = Kb + (size_t)kt * BK * D_DIM;
#pragma unroll 8
      for (int i = 0; i < 16; ++i) {
        int u = i * NTHREADS + tid;
        int key = u >> 8;
        int c = u & 255;
        float4 v = *(const float4*)(Ks + key * D_DIM + c * 4);
        *(uint2*)&Ksh[key * KST + c * 4] = make_uint2(pk2(v.x, v.y), pk2(v.z, v.w));
      }
      // ---- stage V tile transposed: Vt[d][key] bf16 ----
      const float* Vs = Vb + (size_t)kt * BK * D_DIM;
#pragma unroll 8
      for (int i = 0; i < 32; ++i) {
        int u = i * NTHREADS + tid;
        int kp = u >> 10;      // key pair 0..15
        int d = u & 1023;
        float a = Vs[kp * 2 * D_DIM + d];
        float c2 = Vs[(kp * 2 + 1) * D_DIM + d];
        *(u32*)&Vtsh[d * VST + kp * 2] = pk2(a, c2);
      }
      // zero score buffer + flags
      int q = tid >> 3, k4 = (tid & 7) * 4;
      *(int4*)&Ssh[q * SST + k4] = make_int4(0, 0, 0, 0);
      if (tid < 4) fsh[tid] = 0;
    }
    __syncthreads();  // (2) tiles staged

    // ---- QK^T partial over this wave's 128-d slice, reduce via native int LDS atomics ----
    // n-halves split to cap live sp registers at 16.
#pragma unroll
    for (int nb = 0; nb < 2; ++nb) {
      f32x4 sp[4];
#pragma unroll
      for (int m = 0; m < 4; ++m) sp[m] = fzero;
#pragma unroll
      for (int ks = 0; ks < 4; ++ks) {
        int dcol = wave * 128 + ks * 32 + quad * 8;
        int4 kb = *(int4*)&Ksh[(nb * 16 + r) * KST + dcol];
#pragma unroll
        for (int m = 0; m < 4; ++m) sp[m] = mfma16(qf[m][ks], kb, sp[m]);
      }
#pragma unroll
      for (int m = 0; m < 4; ++m)
#pragma unroll
        for (int i = 0; i < 4; ++i) {
          int v = __float2int_rn(sp[m][i] * SFIX);
          atomicAdd(&Ssh[(m * 16 + quad * 4 + i) * SST + nb * 16 + r], v);
        }
    }
    __syncthreads();  // (3) S complete

    // ---- online softmax: 8 threads per row ----
    {
      int q = tid >> 3, kk = (tid & 7) * 4;
      int4 sv = *(int4*)&Ssh[q * SST + kk];
      int qglob = q0 + q, kglob = kt * BK + kk;
      float e0 = (kglob <= qglob) ? (float)sv.x * SCI : -1e30f;
      float e1 = (kglob + 1 <= qglob) ? (float)sv.y * SCI : -1e30f;
      float e2 = (kglob + 2 <= qglob) ? (float)sv.z * SCI : -1e30f;
      float e3 = (kglob + 3 <= qglob) ? (float)sv.w * SCI : -1e30f;
      float mx = fmaxf(fmaxf(e0, e1), fmaxf(e2, e3));
      mx = fmaxf(mx, __shfl_xor(mx, 1));
      mx = fmaxf(mx, __shfl_xor(mx, 2));
      mx = fmaxf(mx, __shfl_xor(mx, 4));
      float mprev = msh[q], lprev = lsh[q];
      float mnew = fmaxf(mprev, mx);
      float alpha = exp2f(mprev - mnew);
      float p0 = exp2f(e0 - mnew), p1 = exp2f(e1 - mnew);
      float p2 = exp2f(e2 - mnew), p3 = exp2f(e3 - mnew);
      float sum = (p0 + p1) + (p2 + p3);
      sum += __shfl_xor(sum, 1);
      sum += __shfl_xor(sum, 2);
      sum += __shfl_xor(sum, 4);
      *(uint2*)&Psh[q * PST + kk] = make_uint2(pk2(p0, p1), pk2(p2, p3));
      if ((tid & 7) == 0) {
        msh[q] = mnew;
        lsh[q] = lprev * alpha + sum;
        ash[q] = alpha;
        if (alpha != 1.0f) fsh[q >> 4] = 1;  // same-value racy store: fine
      }
    }
    __syncthreads();  // (4) P/alpha ready

    // ---- conditional O rescale + PV ----
    {
#pragma unroll
      for (int m = 0; m < 4; ++m) {
        if (fsh[m]) {  // wave-uniform; rarely taken after max saturates
          float a0 = ash[m * 16 + quad * 4 + 0];
          float a1 = ash[m * 16 + quad * 4 + 1];
          float a2 = ash[m * 16 + quad * 4 + 2];
          float a3 = ash[m * 16 + quad * 4 + 3];
#pragma unroll
          for (int n = 0; n < 8; ++n) {
            o[m][n][0] *= a0; o[m][n][1] *= a1; o[m][n][2] *= a2; o[m][n][3] *= a3;
          }
        }
      }
      int4 pf[4];
#pragma unroll
      for (int m = 0; m < 4; ++m)
        pf[m] = *(int4*)&Psh[(m * 16 + r) * PST + quad * 8];
#pragma unroll
      for (int n = 0; n < 8; ++n) {
        const unsigned short* vp = &Vtsh[(wave * 128 + n * 16 + r) * VST + quad * 8];
        int4 vb = make_int4(*(const u32*)vp, *(const u32*)(vp + 2),
                            *(const u32*)(vp + 4), *(const u32*)(vp + 6));
#pragma unroll
        for (int m = 0; m < 4; ++m) o[m][n] = mfma16(pf[m], vb, o[m][n]);
      }
    }
  }

  // ---- epilogue: O / l ----
#pragma unroll
  for (int m = 0; m < 4; ++m) {
    float inv0 = 1.0f / lsh[m * 16 + quad * 4 + 0];
    float inv1 = 1.0f / lsh[m * 16 + quad * 4 + 1];
    float inv2 = 1.0f / lsh[m * 16 + quad * 4 + 2];
    float inv3 = 1.0f / lsh[m * 16 + quad * 4 + 3];
#pragma unroll
    for (int n = 0; n < 8; ++n) {
      size_t row = (size_t)q0 + m * 16 + quad * 4;
      size_t col = (size_t)wave * 128 + n * 16 + r;
      Ob[(row + 0) * D_DIM + col] = o[m][n][0] * inv0;
      Ob[(row + 1) * D_DIM + col] = o[m][n][1] * inv1;
      Ob[(row + 2) * D_DIM + col] = o[m][n][2] * inv2;
      Ob[(row + 3) * D_DIM + col] = o[m][n][3] * inv3;
    }
  }
}

extern "C" void kernel_launch(void* const* d_in, const int* in_sizes, int n_in,
                              void* d_out, int out_size, void* d_ws, size_t ws_size,
                              hipStream_t stream) {
  const float* Q = (const float*)d_in[0];
  const float* K = (const float*)d_in[1];
  const float* V = (const float*)d_in[2];
  float* O = (float*)d_out;
  int B = in_sizes[0] / (L_SEQ * D_DIM);

  hipFuncSetAttribute((const void*)fa_fwd, hipFuncAttributeMaxDynamicSharedMemorySize,
                      LDS_TOTAL);

  dim3 grid(L_SEQ / BQ, B);
  fa_fwd<<<grid, NTHREADS, LDS_TOTAL, stream>>>(Q, K, V, O);
}